// Round 2
// baseline (9226.997 us; speedup 1.0000x reference)
//
#include <hip/hip_runtime.h>

#define B_  64
#define T_  512
#define D_  64
#define U_  256
#define G4  1024   // 4*U

typedef __attribute__((ext_vector_type(2))) float f32x2;
typedef __attribute__((ext_vector_type(4))) float f32x4;

// ---------------------------------------------------------------------------
// Kernel 1: precompute xz[t*B+b][g] = bias[g] + sum_d x[b][t][d] * W[d][g]
// ---------------------------------------------------------------------------
__global__ __launch_bounds__(256) void xz_kernel(const float* __restrict__ x,
                                                 const float* __restrict__ W,
                                                 const float* __restrict__ bias,
                                                 float* __restrict__ xz) {
    __shared__ float xt[16][D_];
    const int g    = blockIdx.x * 256 + threadIdx.x;
    const int row0 = blockIdx.y * 16;

    #pragma unroll
    for (int j = 0; j < 4; ++j) {
        int e = threadIdx.x + 256 * j;          // 0..1023
        int r = e >> 6, d = e & 63;
        int row = row0 + r;
        int t = row >> 6, b = row & 63;         // row = t*64 + b
        xt[r][d] = x[((size_t)b * T_ + t) * D_ + d];
    }
    __syncthreads();

    float acc[16];
    #pragma unroll
    for (int r = 0; r < 16; ++r) acc[r] = 0.f;

    for (int d = 0; d < D_; ++d) {
        float w = W[(size_t)d * G4 + g];        // coalesced across g
        #pragma unroll
        for (int r = 0; r < 16; ++r) acc[r] += xt[r][d] * w;
    }

    float bg = bias[g];
    #pragma unroll
    for (int r = 0; r < 16; ++r)
        xz[(size_t)(row0 + r) * G4 + g] = acc[r] + bg;
}

// ---------------------------------------------------------------------------
// Kernel 2: sequential LSTM scan. One workgroup (1024 threads) per batch
// element. Thread g owns gate column g; U column g lives in REGISTERS
// (128 x f32x2 = 256 VGPRs) loaded once before the t-loop. Per step the
// inner product is 64 LDS broadcast reads + 128 packed-fp32 FMAs.
// ---------------------------------------------------------------------------
__device__ __forceinline__ float sigmoidf_(float z) {
    return 1.f / (1.f + __expf(-z));
}

template <bool PRE>
__global__ __launch_bounds__(1024) void lstm_kernel(
        const float* __restrict__ x,
        const float* __restrict__ W,
        const float* __restrict__ Um,
        const float* __restrict__ bias,
        const float* __restrict__ dw,
        const float* __restrict__ dbp,
        const float* __restrict__ xz,
        float* __restrict__ out) {
    __shared__ __align__(16) float h_s[U_];
    __shared__ float z_s[G4];
    __shared__ float pd_s[U_];

    const int g = threadIdx.x;      // 0..1023 gate column
    const int b = blockIdx.x;       // batch element

    float bg = 0.f;
    if (!PRE) bg = bias[g];
    const float dwr = (g < U_) ? dw[g] : 0.f;
    const float db0 = dbp[0];

    // ---- U column g -> registers (one-time). u_reg[k] = {U[2k][g], U[2k+1][g]}
    f32x2 u_reg[U_ / 2];
    {
        const float* Ucol = Um + g;
        #pragma unroll
        for (int k = 0; k < U_ / 2; ++k) {
            u_reg[k].x = Ucol[(size_t)(2 * k)     * G4];
            u_reg[k].y = Ucol[(size_t)(2 * k + 1) * G4];
        }
    }

    float c = 0.f;                  // persistent cell state for u = g (g<256)
    if (g < U_) h_s[g] = 0.f;
    __syncthreads();

    // prefetch first xz
    float xzt;
    if (PRE) xzt = xz[(size_t)b * G4 + g];   // t=0 row: (0*B+b)*G4

    for (int t = 0; t < T_; ++t) {
        // prefetch next step's xz (hides L2/HBM latency under the k-loop)
        float xzn = 0.f;
        if (PRE) {
            int tn = (t + 1 < T_) ? t + 1 : t;
            xzn = xz[((size_t)tn * B_ + b) * G4 + g];
        }

        f32x2 acc0, acc1;
        if (PRE) {
            acc0 = (f32x2){xzt, 0.f};
            acc1 = (f32x2){0.f, 0.f};
        } else {
            acc0 = (f32x2){bg, 0.f};
            acc1 = (f32x2){0.f, 0.f};
            const float* xrow = x + ((size_t)b * T_ + t) * D_;
            #pragma unroll 8
            for (int d = 0; d < D_; d += 2) {
                acc0.x += xrow[d]     * W[(size_t)d       * G4 + g];
                acc0.y += xrow[d + 1] * W[(size_t)(d + 1) * G4 + g];
            }
        }

        // ---- z_g = xz + h @ U (column g), all-register U ----
        #pragma unroll
        for (int kk = 0; kk < U_ / 4; ++kk) {
            f32x4 h4 = *(const f32x4*)&h_s[4 * kk];   // uniform-address broadcast
            f32x2 hlo = {h4.x, h4.y};
            f32x2 hhi = {h4.z, h4.w};
            acc0 += hlo * u_reg[2 * kk];
            acc1 += hhi * u_reg[2 * kk + 1];
        }
        z_s[g] = (acc0.x + acc1.x) + (acc0.y + acc1.y);
        __syncthreads();            // z ready

        // ---- gates + state update (threads u < 256) ----
        if (g < U_) {
            float zi = z_s[g];
            float zf = z_s[U_ + g];
            float zg = z_s[2 * U_ + g];
            float zo = z_s[3 * U_ + g];
            float ig = sigmoidf_(zi);
            float fg = sigmoidf_(zf);
            float gg = fmaxf(zg, 0.f);
            float og = sigmoidf_(zo);
            c = fg * c + ig * gg;
            float h = og * fmaxf(c, 0.f);
            h_s[g]  = h;
            pd_s[g] = h * dwr;
        }
        __syncthreads();            // h (and pd) ready

        // ---- dense output: sigma[b][t] = sum_u h[u]*dw[u] + db ----
        if (g < 64) {
            float s = pd_s[g] + pd_s[g + 64] + pd_s[g + 128] + pd_s[g + 192];
            #pragma unroll
            for (int off = 32; off > 0; off >>= 1)
                s += __shfl_down(s, off);
            if (g == 0) out[(size_t)b * T_ + t] = s + db0;
        }

        xzt = xzn;
    }
}

// ---------------------------------------------------------------------------
extern "C" void kernel_launch(void* const* d_in, const int* in_sizes, int n_in,
                              void* d_out, int out_size, void* d_ws, size_t ws_size,
                              hipStream_t stream) {
    const float* x    = (const float*)d_in[0];
    const float* W    = (const float*)d_in[1];
    const float* Um   = (const float*)d_in[2];
    const float* bias = (const float*)d_in[3];
    const float* dw   = (const float*)d_in[4];
    const float* db   = (const float*)d_in[5];
    float* out = (float*)d_out;

    const size_t need = (size_t)T_ * B_ * G4 * sizeof(float);   // 128 MiB
    if (ws_size >= need) {
        float* xz = (float*)d_ws;
        dim3 gridX(G4 / 256, (T_ * B_) / 16);
        xz_kernel<<<gridX, 256, 0, stream>>>(x, W, bias, xz);
        lstm_kernel<true><<<B_, 1024, 0, stream>>>(x, W, Um, bias, dw, db, xz, out);
    } else {
        lstm_kernel<false><<<B_, 1024, 0, stream>>>(x, W, Um, bias, dw, db, nullptr, out);
    }
}

// Round 3
// 1092.282 us; speedup vs baseline: 8.4475x; 8.4475x over previous
//
#include <hip/hip_runtime.h>

#define B_  64
#define T_  512
#define D_  64
#define U_  256
#define G4  1024   // 4*U
#define NT  512    // threads per LSTM workgroup
#define RP  96     // f16x2 pairs per column held in REGISTERS (k = 0..191)
#define LP  32     // f16x2 pairs per column held in LDS       (k = 192..255)

typedef _Float16 f16x2 __attribute__((ext_vector_type(2)));
union U32H2 { unsigned int u; f16x2 h; };

__device__ __forceinline__ float dot2(unsigned int a, unsigned int b, float c) {
    U32H2 ua, ub; ua.u = a; ub.u = b;
#if __has_builtin(__builtin_amdgcn_fdot2)
    return __builtin_amdgcn_fdot2(ua.h, ub.h, c, false);
#else
    return c + (float)ua.h.x * (float)ub.h.x + (float)ua.h.y * (float)ub.h.y;
#endif
}

__device__ __forceinline__ float sigmoidf_(float z) {
    return 1.f / (1.f + __expf(-z));
}

// ---------------------------------------------------------------------------
// Kernel 1: xz[t*B+b][g] = bias[g] + sum_d x[b][t][d] * W[d][g]   (fp32 exact)
// ---------------------------------------------------------------------------
__global__ __launch_bounds__(256) void xz_kernel(const float* __restrict__ x,
                                                 const float* __restrict__ W,
                                                 const float* __restrict__ bias,
                                                 float* __restrict__ xz) {
    __shared__ float xt[16][D_];
    const int g    = blockIdx.x * 256 + threadIdx.x;
    const int row0 = blockIdx.y * 16;

    #pragma unroll
    for (int j = 0; j < 4; ++j) {
        int e = threadIdx.x + 256 * j;
        int r = e >> 6, d = e & 63;
        int row = row0 + r;
        int t = row >> 6, b = row & 63;         // row = t*64 + b
        xt[r][d] = x[((size_t)b * T_ + t) * D_ + d];
    }
    __syncthreads();

    float acc[16];
    #pragma unroll
    for (int r = 0; r < 16; ++r) acc[r] = 0.f;

    for (int d = 0; d < D_; ++d) {
        float w = W[(size_t)d * G4 + g];
        #pragma unroll
        for (int r = 0; r < 16; ++r) acc[r] += xt[r][d] * w;
    }

    float bg = bias[g];
    #pragma unroll
    for (int r = 0; r < 16; ++r)
        xz[(size_t)(row0 + r) * G4 + g] = acc[r] + bg;
}

// ---------------------------------------------------------------------------
// Kernel 2: sequential scan, one WG (512 thr) per batch element.
// U is CU-resident in f16: 96 pairs/col in VGPRs + 32 pairs/col in LDS.
// Thread tau owns gate columns tau and tau+512. fp32 accumulate via v_dot2.
// ---------------------------------------------------------------------------
__global__ __launch_bounds__(NT, 2) void lstm_kernel(
        const float* __restrict__ Um,
        const float* __restrict__ dw,
        const float* __restrict__ dbp,
        const float* __restrict__ xz,
        float* __restrict__ out) {
    // dynamic LDS: [lds_u: LP*G4 u32][h16: 256 f16][z: G4 f32][pd: 256 f32]
    extern __shared__ __align__(16) char smem[];
    unsigned int* lds_u = (unsigned int*)smem;                    // 128 KB
    _Float16*    h16_s  = (_Float16*)(smem + LP * G4 * 4);        // 512 B
    float*       z_s    = (float*)(smem + LP * G4 * 4 + 512);     // 4 KB
    float*       pd_s   = (float*)(smem + LP * G4 * 4 + 512 + G4 * 4); // 1 KB

    const int tau = threadIdx.x;
    const int b   = blockIdx.x;
    const int c0  = tau;
    const int c1  = tau + NT;

    // ---- one-time: U columns c0,c1 -> registers as packed f16x2 ----
    unsigned int u0r[RP], u1r[RP];
    #pragma unroll
    for (int p = 0; p < RP; ++p) {
        U32H2 a, c;
        a.h = f16x2{(_Float16)Um[(size_t)(2 * p) * G4 + c0],
                    (_Float16)Um[(size_t)(2 * p + 1) * G4 + c0]};
        c.h = f16x2{(_Float16)Um[(size_t)(2 * p) * G4 + c1],
                    (_Float16)Um[(size_t)(2 * p + 1) * G4 + c1]};
        u0r[p] = a.u;
        u1r[p] = c.u;
    }
    // ---- one-time: U rows 192..255 -> LDS as packed f16x2 ----
    for (int i = tau; i < LP * G4; i += NT) {
        int j = i >> 10, c = i & (G4 - 1);
        U32H2 a;
        a.h = f16x2{(_Float16)Um[(size_t)(2 * RP + 2 * j) * G4 + c],
                    (_Float16)Um[(size_t)(2 * RP + 2 * j + 1) * G4 + c]};
        lds_u[(size_t)j * G4 + c] = a.u;
    }
    if (tau < U_) h16_s[tau] = (_Float16)0.f;

    const float dwr = (tau < U_) ? dw[tau] : 0.f;
    const float db0 = dbp[0];
    float c_state = 0.f;

    float xz0 = xz[(size_t)b * G4 + c0];    // t = 0 row
    float xz1 = xz[(size_t)b * G4 + c1];
    __syncthreads();

    for (int t = 0; t < T_; ++t) {
        // prefetch next xz under the dot loop
        int tn = (t + 1 < T_) ? t + 1 : t;
        float xz0n = xz[((size_t)tn * B_ + b) * G4 + c0];
        float xz1n = xz[((size_t)tn * B_ + b) * G4 + c1];

        // ---- z = xz + h @ U for columns c0, c1 ----
        float a00 = xz0, a01 = 0.f, a02 = 0.f, a03 = 0.f;
        float a10 = xz1, a11 = 0.f, a12 = 0.f, a13 = 0.f;
        const uint4* h16q = (const uint4*)h16_s;    // 8 halves per read
        #pragma unroll
        for (int j = 0; j < 32; ++j) {
            uint4 hv = h16q[j];                     // uniform broadcast
            unsigned int hp[4] = {hv.x, hv.y, hv.z, hv.w};
            #pragma unroll
            for (int e = 0; e < 4; ++e) {
                const int p = 4 * j + e;            // pair index 0..127
                unsigned int up0, up1;
                if (p < RP) {
                    up0 = u0r[p]; up1 = u1r[p];
                } else {
                    up0 = lds_u[(size_t)(p - RP) * G4 + c0];
                    up1 = lds_u[(size_t)(p - RP) * G4 + c1];
                }
                if (e == 0)      { a00 = dot2(up0, hp[e], a00); a10 = dot2(up1, hp[e], a10); }
                else if (e == 1) { a01 = dot2(up0, hp[e], a01); a11 = dot2(up1, hp[e], a11); }
                else if (e == 2) { a02 = dot2(up0, hp[e], a02); a12 = dot2(up1, hp[e], a12); }
                else             { a03 = dot2(up0, hp[e], a03); a13 = dot2(up1, hp[e], a13); }
            }
        }
        z_s[c0] = (a00 + a01) + (a02 + a03);
        z_s[c1] = (a10 + a11) + (a12 + a13);
        __syncthreads();                            // z ready

        // ---- gates + state update (threads tau < 256, u = tau) ----
        if (tau < U_) {
            float zi = z_s[tau];
            float zf = z_s[U_ + tau];
            float zg = z_s[2 * U_ + tau];
            float zo = z_s[3 * U_ + tau];
            float ig = sigmoidf_(zi);
            float fg = sigmoidf_(zf);
            float gg = fmaxf(zg, 0.f);
            float og = sigmoidf_(zo);
            c_state = fg * c_state + ig * gg;
            float h = og * fmaxf(c_state, 0.f);
            h16_s[tau] = (_Float16)h;
            pd_s[tau]  = h * dwr;
        }
        __syncthreads();                            // h16 (and pd) ready

        // ---- dense: sigma[b][t] = sum_u h[u]*dw[u] + db ----
        if (tau < 64) {
            float s = pd_s[tau] + pd_s[tau + 64] + pd_s[tau + 128] + pd_s[tau + 192];
            #pragma unroll
            for (int off = 32; off > 0; off >>= 1)
                s += __shfl_down(s, off);
            if (tau == 0) out[(size_t)b * T_ + t] = s + db0;
        }

        xz0 = xz0n; xz1 = xz1n;
    }
}

// ---------------------------------------------------------------------------
// Fallback (no workspace): round-1 style streaming kernel, correctness only.
// ---------------------------------------------------------------------------
__global__ __launch_bounds__(1024) void lstm_fallback(
        const float* __restrict__ x,  const float* __restrict__ W,
        const float* __restrict__ Um, const float* __restrict__ bias,
        const float* __restrict__ dw, const float* __restrict__ dbp,
        float* __restrict__ out) {
    __shared__ float h_s[U_];
    __shared__ float z_s[G4];
    __shared__ float pd_s[U_];
    const int g = threadIdx.x;
    const int b = blockIdx.x;
    const float bg  = bias[g];
    const float dwr = (g < U_) ? dw[g] : 0.f;
    const float db0 = dbp[0];
    float c = 0.f;
    if (g < U_) h_s[g] = 0.f;
    __syncthreads();
    const float* Ucol = Um + g;
    for (int t = 0; t < T_; ++t) {
        float acc = bg;
        const float* xrow = x + ((size_t)b * T_ + t) * D_;
        for (int d = 0; d < D_; ++d) acc += xrow[d] * W[(size_t)d * G4 + g];
        for (int k = 0; k < U_; ++k) acc += h_s[k] * Ucol[(size_t)k * G4];
        z_s[g] = acc;
        __syncthreads();
        if (g < U_) {
            float ig = sigmoidf_(z_s[g]);
            float fg = sigmoidf_(z_s[U_ + g]);
            float gg = fmaxf(z_s[2 * U_ + g], 0.f);
            float og = sigmoidf_(z_s[3 * U_ + g]);
            c = fg * c + ig * gg;
            float h = og * fmaxf(c, 0.f);
            h_s[g] = h; pd_s[g] = h * dwr;
        }
        __syncthreads();
        if (g < 64) {
            float s = pd_s[g] + pd_s[g + 64] + pd_s[g + 128] + pd_s[g + 192];
            #pragma unroll
            for (int off = 32; off > 0; off >>= 1) s += __shfl_down(s, off);
            if (g == 0) out[(size_t)b * T_ + t] = s + db0;
        }
        __syncthreads();
    }
}

// ---------------------------------------------------------------------------
extern "C" void kernel_launch(void* const* d_in, const int* in_sizes, int n_in,
                              void* d_out, int out_size, void* d_ws, size_t ws_size,
                              hipStream_t stream) {
    const float* x    = (const float*)d_in[0];
    const float* W    = (const float*)d_in[1];
    const float* Um   = (const float*)d_in[2];
    const float* bias = (const float*)d_in[3];
    const float* dw   = (const float*)d_in[4];
    const float* db   = (const float*)d_in[5];
    float* out = (float*)d_out;

    const size_t need = (size_t)T_ * B_ * G4 * sizeof(float);   // 128 MiB
    if (ws_size >= need) {
        float* xz = (float*)d_ws;
        dim3 gridX(G4 / 256, (T_ * B_) / 16);
        xz_kernel<<<gridX, 256, 0, stream>>>(x, W, bias, xz);

        const size_t smem = (size_t)LP * G4 * 4 + 512 + G4 * 4 + U_ * 4; // ~136 KB
        static bool attr_done = false;  // idempotent config, not a work guard
        if (!attr_done) {
            hipFuncSetAttribute((const void*)lstm_kernel,
                                hipFuncAttributeMaxDynamicSharedMemorySize,
                                (int)(160 * 1024));
            attr_done = true;
        }
        lstm_kernel<<<B_, NT, smem, stream>>>(Um, dw, db, xz, out);
    } else {
        lstm_fallback<<<B_, 1024, 0, stream>>>(x, W, Um, bias, dw, db, out);
    }
}

// Round 4
// 1087.196 us; speedup vs baseline: 8.4870x; 1.0047x over previous
//
#include <hip/hip_runtime.h>

#define B_  64
#define T_  512
#define D_  64
#define U_  256
#define G4  1024   // 4*U
#define NT  512    // threads per LSTM workgroup (8 waves, 2/SIMD)
#define NREGC 13   // register-resident columns per 16-col group
#define NLDSC 3    // LDS-resident columns per 16-col group
#define LDSU_STRIDE 132          // u32 stride per LDS column (128 + 4 pad)
#define NLCOL (64 * NLDSC)       // 192 LDS-resident columns total

// LDS layout (bytes)
#define LDSU_BYTES (NLCOL * LDSU_STRIDE * 4)        // 101376
#define H_OFF   LDSU_BYTES                          // 8 slices x 80 B
#define Z_OFF   (H_OFF + 640)                       // 1024 f32
#define PD_OFF  (Z_OFF + 4096)                      // 256 f32
#define SMEM_TOTAL (PD_OFF + 1024)                  // 107136

typedef _Float16 f16x2 __attribute__((ext_vector_type(2)));
union U32H2 { unsigned int u; f16x2 h; unsigned short s[2]; };

__device__ __forceinline__ float dot2(unsigned int a, unsigned int b, float c) {
    U32H2 ua, ub; ua.u = a; ub.u = b;
#if __has_builtin(__builtin_amdgcn_fdot2)
    return __builtin_amdgcn_fdot2(ua.h, ub.h, c, false);
#else
    return c + (float)ua.h.x * (float)ub.h.x + (float)ua.h.y * (float)ub.h.y;
#endif
}

template <int CTRL>
__device__ __forceinline__ float dpp_mov_f32(float x) {
    int m = __builtin_amdgcn_update_dpp(0, __float_as_int(x), CTRL, 0xF, 0xF, true);
    return __int_as_float(m);
}

__device__ __forceinline__ float sigmoidf_(float z) {
    return 1.f / (1.f + __expf(-z));
}

// ---------------------------------------------------------------------------
// Kernel 1: xz[t*B+b][g] = bias[g] + sum_d x[b][t][d] * W[d][g]   (fp32 exact)
// ---------------------------------------------------------------------------
__global__ __launch_bounds__(256) void xz_kernel(const float* __restrict__ x,
                                                 const float* __restrict__ W,
                                                 const float* __restrict__ bias,
                                                 float* __restrict__ xz) {
    __shared__ float xt[16][D_];
    const int g    = blockIdx.x * 256 + threadIdx.x;
    const int row0 = blockIdx.y * 16;

    #pragma unroll
    for (int j = 0; j < 4; ++j) {
        int e = threadIdx.x + 256 * j;
        int r = e >> 6, d = e & 63;
        int row = row0 + r;
        int t = row >> 6, b = row & 63;         // row = t*64 + b
        xt[r][d] = x[((size_t)b * T_ + t) * D_ + d];
    }
    __syncthreads();

    float acc[16];
    #pragma unroll
    for (int r = 0; r < 16; ++r) acc[r] = 0.f;

    for (int d = 0; d < D_; ++d) {
        float w = W[(size_t)d * G4 + g];
        #pragma unroll
        for (int r = 0; r < 16; ++r) acc[r] += xt[r][d] * w;
    }

    float bg = bias[g];
    #pragma unroll
    for (int r = 0; r < 16; ++r)
        xz[(size_t)(row0 + r) * G4 + g] = acc[r] + bg;
}

// ---------------------------------------------------------------------------
// Kernel 2: sequential scan, one WG (512 thr) per batch element.
// thread tau = (g = tau>>3, r = tau&7). Group g owns columns 16g..16g+15;
// slice r owns k in [32r, 32r+32) (16 f16-pairs). U is f16: 13 cols/group in
// VGPRs (208 u32/thread), 3 cols/group in LDS (b128 reads). Cross-slice
// reduction via DPP (VALU pipe). fp32 accumulate via v_dot2_f32_f16.
// ---------------------------------------------------------------------------
__global__ __launch_bounds__(NT, 2)
__attribute__((amdgpu_waves_per_eu(2, 2)))
void lstm_kernel(
        const float* __restrict__ Um,
        const float* __restrict__ dw,
        const float* __restrict__ dbp,
        const float* __restrict__ xz,
        float* __restrict__ out) {
    extern __shared__ __align__(16) char smem[];
    unsigned int* lds_u = (unsigned int*)smem;
    char*  h_all = smem + H_OFF;               // 8 slices x (64 B + 16 B pad)
    float* z_s   = (float*)(smem + Z_OFF);
    float* pd_s  = (float*)(smem + PD_OFF);

    const int tau = threadIdx.x;
    const int b   = blockIdx.x;
    const int g   = tau >> 3;
    const int r   = tau & 7;

    // ---- one-time: register-resident U columns (13 per group) ----
    unsigned int u_reg[NREGC * 16];
    {
        #pragma unroll
        for (int j = 0; j < NREGC; ++j) {
            const int col = 16 * g + j;
            #pragma unroll
            for (int p = 0; p < 16; ++p) {
                const int pr = 16 * r + p;      // pair index (k = 2*pr, 2*pr+1)
                U32H2 a;
                a.h = f16x2{(_Float16)Um[(size_t)(2 * pr) * G4 + col],
                            (_Float16)Um[(size_t)(2 * pr + 1) * G4 + col]};
                u_reg[j * 16 + p] = a.u;
            }
        }
    }
    // ---- one-time: LDS-resident U columns (3 per group) ----
    for (int i = tau; i < NLCOL * 128; i += NT) {
        const int cidx = i >> 7, p = i & 127;
        const int col  = 16 * (cidx / 3) + NREGC + (cidx % 3);
        U32H2 a;
        a.h = f16x2{(_Float16)Um[(size_t)(2 * p) * G4 + col],
                    (_Float16)Um[(size_t)(2 * p + 1) * G4 + col]};
        lds_u[cidx * LDSU_STRIDE + p] = a.u;
    }
    // ---- init h = 0 ----
    if (tau < U_) {
        ((unsigned short*)h_all)[(tau >> 5) * 40 + (tau & 31)] = 0;
    }

    const float dwr = (tau < U_) ? dw[tau] : 0.f;
    const float db0 = dbp[0];
    float c_state = 0.f;

    // per-thread LDS-U bases (slice r of each of the 3 LDS cols)
    const unsigned int* lu0 = lds_u + (3 * g + 0) * LDSU_STRIDE + 16 * r;
    const unsigned int* lu1 = lds_u + (3 * g + 1) * LDSU_STRIDE + 16 * r;
    const unsigned int* lu2 = lds_u + (3 * g + 2) * LDSU_STRIDE + 16 * r;
    const uint4* hq = (const uint4*)(h_all + r * 80);   // 4 quads of this slice
    const int c2 = 16 * g + 2 * r;                      // cols this thread writes

    // xz for t=0
    float2 xzc = *(const float2*)(xz + (size_t)b * G4 + c2);
    __syncthreads();

    for (int t = 0; t < T_; ++t) {
        // prefetch next step's xz
        const int tn = (t + 1 < T_) ? t + 1 : t;
        float2 xzn = *(const float2*)(xz + ((size_t)tn * B_ + b) * G4 + c2);

        // ---- partial dots: acc[j] = sum over this slice's 32 k of h*U ----
        float acc[16];
        #pragma unroll
        for (int j = 0; j < 16; ++j) acc[j] = 0.f;

        #pragma unroll
        for (int i = 0; i < 4; ++i) {           // 4 pairs per chunk
            const uint4 h4 = hq[i];
            const unsigned int hp0 = h4.x, hp1 = h4.y, hp2 = h4.z, hp3 = h4.w;
            #pragma unroll
            for (int j = 0; j < NREGC; ++j) {
                acc[j] = dot2(u_reg[j * 16 + 4 * i + 0], hp0, acc[j]);
                acc[j] = dot2(u_reg[j * 16 + 4 * i + 1], hp1, acc[j]);
                acc[j] = dot2(u_reg[j * 16 + 4 * i + 2], hp2, acc[j]);
                acc[j] = dot2(u_reg[j * 16 + 4 * i + 3], hp3, acc[j]);
            }
            {
                const uint4 uq0 = *(const uint4*)(lu0 + 4 * i);
                acc[13] = dot2(uq0.x, hp0, acc[13]);
                acc[13] = dot2(uq0.y, hp1, acc[13]);
                acc[13] = dot2(uq0.z, hp2, acc[13]);
                acc[13] = dot2(uq0.w, hp3, acc[13]);
                const uint4 uq1 = *(const uint4*)(lu1 + 4 * i);
                acc[14] = dot2(uq1.x, hp0, acc[14]);
                acc[14] = dot2(uq1.y, hp1, acc[14]);
                acc[14] = dot2(uq1.z, hp2, acc[14]);
                acc[14] = dot2(uq1.w, hp3, acc[14]);
                const uint4 uq2 = *(const uint4*)(lu2 + 4 * i);
                acc[15] = dot2(uq2.x, hp0, acc[15]);
                acc[15] = dot2(uq2.y, hp1, acc[15]);
                acc[15] = dot2(uq2.z, hp2, acc[15]);
                acc[15] = dot2(uq2.w, hp3, acc[15]);
            }
        }

        // ---- cross-slice butterfly over the 8-lane group (VALU/DPP pipe) ----
        #pragma unroll
        for (int j = 0; j < 16; ++j) {
            float v = acc[j];
            v += dpp_mov_f32<0xB1>(v);     // quad_perm [1,0,3,2]  (xor 1)
            v += dpp_mov_f32<0x4E>(v);     // quad_perm [2,3,0,1]  (xor 2)
            v += dpp_mov_f32<0x141>(v);    // row_half_mirror      (xor 4-ish)
            acc[j] = v;
        }

        // lane r writes columns c2, c2+1 -> select acc[2r], acc[2r+1]
        float z0 = acc[0], z1 = acc[1];
        #pragma unroll
        for (int rr = 1; rr < 8; ++rr) {
            if (r == rr) { z0 = acc[2 * rr]; z1 = acc[2 * rr + 1]; }
        }
        z0 += xzc.x;
        z1 += xzc.y;
        *(float2*)(z_s + c2) = float2{z0, z1};
        __syncthreads();                        // z ready

        // ---- gates + state update (threads tau < 256, u = tau) ----
        if (tau < U_) {
            const int u = tau;
            float zi = z_s[u];
            float zf = z_s[U_ + u];
            float zg = z_s[2 * U_ + u];
            float zo = z_s[3 * U_ + u];
            float ig = sigmoidf_(zi);
            float fg = sigmoidf_(zf);
            float gg = fmaxf(zg, 0.f);
            float og = sigmoidf_(zo);
            c_state = fg * c_state + ig * gg;
            float h = og * fmaxf(c_state, 0.f);
            U32H2 hb; hb.h = f16x2{(_Float16)h, (_Float16)h};
            ((unsigned short*)h_all)[(u >> 5) * 40 + (u & 31)] = hb.s[0];
            pd_s[u] = h * dwr;
        }
        __syncthreads();                        // h (and pd) ready

        // ---- dense: sigma[b][t] = sum_u h[u]*dw[u] + db ----
        if (tau < 64) {
            float s = pd_s[tau] + pd_s[tau + 64] + pd_s[tau + 128] + pd_s[tau + 192];
            #pragma unroll
            for (int off = 32; off > 0; off >>= 1)
                s += __shfl_down(s, off);
            if (tau == 0) out[(size_t)b * T_ + t] = s + db0;
        }

        xzc = xzn;
    }
}

// ---------------------------------------------------------------------------
// Fallback (no workspace): streaming kernel, correctness only.
// ---------------------------------------------------------------------------
__global__ __launch_bounds__(1024) void lstm_fallback(
        const float* __restrict__ x,  const float* __restrict__ W,
        const float* __restrict__ Um, const float* __restrict__ bias,
        const float* __restrict__ dw, const float* __restrict__ dbp,
        float* __restrict__ out) {
    __shared__ float h_s[U_];
    __shared__ float z_s2[G4];
    __shared__ float pd_s2[U_];
    const int g = threadIdx.x;
    const int b = blockIdx.x;
    const float bg  = bias[g];
    const float dwr = (g < U_) ? dw[g] : 0.f;
    const float db0 = dbp[0];
    float c = 0.f;
    if (g < U_) h_s[g] = 0.f;
    __syncthreads();
    const float* Ucol = Um + g;
    for (int t = 0; t < T_; ++t) {
        float acc = bg;
        const float* xrow = x + ((size_t)b * T_ + t) * D_;
        for (int d = 0; d < D_; ++d) acc += xrow[d] * W[(size_t)d * G4 + g];
        for (int k = 0; k < U_; ++k) acc += h_s[k] * Ucol[(size_t)k * G4];
        z_s2[g] = acc;
        __syncthreads();
        if (g < U_) {
            float ig = sigmoidf_(z_s2[g]);
            float fg = sigmoidf_(z_s2[U_ + g]);
            float gg = fmaxf(z_s2[2 * U_ + g], 0.f);
            float og = sigmoidf_(z_s2[3 * U_ + g]);
            c = fg * c + ig * gg;
            float h = og * fmaxf(c, 0.f);
            h_s[g] = h; pd_s2[g] = h * dwr;
        }
        __syncthreads();
        if (g < 64) {
            float s = pd_s2[g] + pd_s2[g + 64] + pd_s2[g + 128] + pd_s2[g + 192];
            #pragma unroll
            for (int off = 32; off > 0; off >>= 1) s += __shfl_down(s, off);
            if (g == 0) out[(size_t)b * T_ + t] = s + db0;
        }
        __syncthreads();
    }
}

// ---------------------------------------------------------------------------
extern "C" void kernel_launch(void* const* d_in, const int* in_sizes, int n_in,
                              void* d_out, int out_size, void* d_ws, size_t ws_size,
                              hipStream_t stream) {
    const float* x    = (const float*)d_in[0];
    const float* W    = (const float*)d_in[1];
    const float* Um   = (const float*)d_in[2];
    const float* bias = (const float*)d_in[3];
    const float* dw   = (const float*)d_in[4];
    const float* db   = (const float*)d_in[5];
    float* out = (float*)d_out;

    const size_t need = (size_t)T_ * B_ * G4 * sizeof(float);   // 128 MiB
    if (ws_size >= need) {
        float* xz = (float*)d_ws;
        dim3 gridX(G4 / 256, (T_ * B_) / 16);
        xz_kernel<<<gridX, 256, 0, stream>>>(x, W, bias, xz);

        static bool attr_done = false;  // idempotent config, not a work guard
        if (!attr_done) {
            hipFuncSetAttribute((const void*)lstm_kernel,
                                hipFuncAttributeMaxDynamicSharedMemorySize,
                                (int)(SMEM_TOTAL + 1024));
            attr_done = true;
        }
        lstm_kernel<<<B_, NT, SMEM_TOTAL, stream>>>(Um, dw, db, xz, out);
    } else {
        lstm_fallback<<<B_, 1024, 0, stream>>>(x, W, Um, bias, dw, db, out);
    }
}

// Round 5
// 1069.814 us; speedup vs baseline: 8.6249x; 1.0162x over previous
//
#include <hip/hip_runtime.h>

#define B_  64
#define T_  512
#define D_  64
#define U_  256
#define G4  1024   // 4*U
#define NT  512    // 8 waves, 2 per SIMD

// ---- LDS map (bytes) ----
// Padded U region: 192 cols (j=12..14 of each 16-col group), slice stride 80B
#define UPAD_BYTES (192 * 640)               // 122880
#define UUNP_OFF   UPAD_BYTES                // col j=15 region, quad-swizzled
#define UUNP_BYTES (64 * 512)                // 32768
#define H_OFF      (UUNP_OFF + UUNP_BYTES)   // 155648: h as 8 slices x 80 B
#define Z_OFF      (H_OFF + 640)             // 156288: z, 1024 f32
#define PD_OFF     (Z_OFF + 4096)            // 160384: pd, 256 f32
#define SMEM_TOTAL (PD_OFF + 1024)           // 161408 <= 163840

typedef _Float16 f16x2 __attribute__((ext_vector_type(2)));
typedef unsigned int ux16 __attribute__((ext_vector_type(16)));
union U32H2 { unsigned int u; f16x2 h; unsigned short s[2]; };

__device__ __forceinline__ float dot2(unsigned int a, unsigned int b, float c) {
    U32H2 ua, ub; ua.u = a; ub.u = b;
#if __has_builtin(__builtin_amdgcn_fdot2)
    return __builtin_amdgcn_fdot2(ua.h, ub.h, c, false);
#else
    return c + (float)ua.h.x * (float)ub.h.x + (float)ua.h.y * (float)ub.h.y;
#endif
}

template <int CTRL>
__device__ __forceinline__ float dpp_mov_f32(float x) {
    int m = __builtin_amdgcn_update_dpp(0, __float_as_int(x), CTRL, 0xF, 0xF, true);
    return __int_as_float(m);
}

__device__ __forceinline__ float sigmoidf_(float z) {
    return 1.f / (1.f + __expf(-z));
}

// ---------------------------------------------------------------------------
// Kernel 1: xz[t*B+b][g] = bias[g] + sum_d x[b][t][d] * W[d][g]   (fp32 exact)
// ---------------------------------------------------------------------------
__global__ __launch_bounds__(256) void xz_kernel(const float* __restrict__ x,
                                                 const float* __restrict__ W,
                                                 const float* __restrict__ bias,
                                                 float* __restrict__ xz) {
    __shared__ float xt[16][D_];
    const int g    = blockIdx.x * 256 + threadIdx.x;
    const int row0 = blockIdx.y * 16;

    #pragma unroll
    for (int j = 0; j < 4; ++j) {
        int e = threadIdx.x + 256 * j;
        int r = e >> 6, d = e & 63;
        int row = row0 + r;
        int t = row >> 6, b = row & 63;         // row = t*64 + b
        xt[r][d] = x[((size_t)b * T_ + t) * D_ + d];
    }
    __syncthreads();

    float acc[16];
    #pragma unroll
    for (int r = 0; r < 16; ++r) acc[r] = 0.f;

    for (int d = 0; d < D_; ++d) {
        float w = W[(size_t)d * G4 + g];
        #pragma unroll
        for (int r = 0; r < 16; ++r) acc[r] += xt[r][d] * w;
    }

    float bg = bias[g];
    #pragma unroll
    for (int r = 0; r < 16; ++r)
        xz[(size_t)(row0 + r) * G4 + g] = acc[r] + bg;
}

// ---------------------------------------------------------------------------
// Kernel 2: sequential scan, one WG (512 thr) per batch element.
// thread tau = (g = tau>>3, r = tau&7). Group g owns cols 16g..16g+15; slice r
// owns pairs [16r,16r+16) (k = 32r..32r+31). U f16: cols j=0..11 in 12 named
// ux16 SSA vectors (192 VGPRs, no alloca -> cannot be demoted to scratch);
// cols 12..15 in LDS. fp32 accumulate via v_dot2_f32_f16; 8-lane DPP reduce.
// ---------------------------------------------------------------------------

// pack U[2*(16r+p)][col], U[2*(16r+p)+1][col] -> u32 of 2 f16
#define PACKP(p_) __extension__ ({                                            \
    U32H2 a_;                                                                 \
    a_.h = f16x2{(_Float16)Um[(size_t)(2 * (16 * r + (p_))) * G4 + col],      \
                 (_Float16)Um[(size_t)(2 * (16 * r + (p_)) + 1) * G4 + col]}; \
    a_.u; })

#define INIT_UCOL(UV, jj) {                                   \
    const int col = 16 * g + (jj);                            \
    UV.s0 = PACKP(0);  UV.s1 = PACKP(1);  UV.s2 = PACKP(2);   \
    UV.s3 = PACKP(3);  UV.s4 = PACKP(4);  UV.s5 = PACKP(5);   \
    UV.s6 = PACKP(6);  UV.s7 = PACKP(7);  UV.s8 = PACKP(8);   \
    UV.s9 = PACKP(9);  UV.sa = PACKP(10); UV.sb = PACKP(11);  \
    UV.sc = PACKP(12); UV.sd = PACKP(13); UV.se = PACKP(14);  \
    UV.sf = PACKP(15); }

#define DOTC(UV, ACC, S0, S1, S2, S3) {      \
    ACC = dot2(UV.S0, hp0, ACC);             \
    ACC = dot2(UV.S1, hp1, ACC);             \
    ACC = dot2(UV.S2, hp2, ACC);             \
    ACC = dot2(UV.S3, hp3, ACC); }

#define DOTQ(Q, ACC) {                       \
    ACC = dot2(Q.x, hp0, ACC);               \
    ACC = dot2(Q.y, hp1, ACC);               \
    ACC = dot2(Q.z, hp2, ACC);               \
    ACC = dot2(Q.w, hp3, ACC); }

#define DOT_CHUNK(I, S0, S1, S2, S3) {                                  \
    const uint4 h4 = hq[I];                                             \
    const unsigned int hp0 = h4.x, hp1 = h4.y, hp2 = h4.z, hp3 = h4.w;  \
    DOTC(u0,  acc0,  S0, S1, S2, S3)                                    \
    DOTC(u1,  acc1,  S0, S1, S2, S3)                                    \
    DOTC(u2,  acc2,  S0, S1, S2, S3)                                    \
    DOTC(u3,  acc3,  S0, S1, S2, S3)                                    \
    DOTC(u4,  acc4,  S0, S1, S2, S3)                                    \
    DOTC(u5,  acc5,  S0, S1, S2, S3)                                    \
    DOTC(u6,  acc6,  S0, S1, S2, S3)                                    \
    DOTC(u7,  acc7,  S0, S1, S2, S3)                                    \
    DOTC(u8,  acc8,  S0, S1, S2, S3)                                    \
    DOTC(u9,  acc9,  S0, S1, S2, S3)                                    \
    DOTC(u10, acc10, S0, S1, S2, S3)                                    \
    DOTC(u11, acc11, S0, S1, S2, S3)                                    \
    { const uint4 q = lqP[I];           DOTQ(q, acc12) }                \
    { const uint4 q = lqP[40 + I];      DOTQ(q, acc13) }                \
    { const uint4 q = lqP[80 + I];      DOTQ(q, acc14) }                \
    { const uint4 q = lqU##I[0];        DOTQ(q, acc15) } }

#define RED(ACC) {                          \
    ACC += dpp_mov_f32<0xB1>(ACC);          \
    ACC += dpp_mov_f32<0x4E>(ACC);          \
    ACC += dpp_mov_f32<0x141>(ACC); }

__global__
__attribute__((amdgpu_flat_work_group_size(NT, NT), amdgpu_waves_per_eu(2, 2)))
void lstm_kernel(
        const float* __restrict__ Um,
        const float* __restrict__ dw,
        const float* __restrict__ dbp,
        const float* __restrict__ xz,
        float* __restrict__ out) {
    extern __shared__ __align__(16) char smem[];
    float*          z_s  = (float*)(smem + Z_OFF);
    float*          pd_s = (float*)(smem + PD_OFF);
    unsigned short* h16  = (unsigned short*)(smem + H_OFF);

    const int tau = threadIdx.x;
    const int b   = blockIdx.x;
    const int g   = tau >> 3;
    const int r   = tau & 7;

    // ---- one-time: register-resident U (cols j=0..11 of group g) ----
    ux16 u0, u1, u2, u3, u4, u5, u6, u7, u8, u9, u10, u11;
    INIT_UCOL(u0, 0)   INIT_UCOL(u1, 1)   INIT_UCOL(u2, 2)
    INIT_UCOL(u3, 3)   INIT_UCOL(u4, 4)   INIT_UCOL(u5, 5)
    INIT_UCOL(u6, 6)   INIT_UCOL(u7, 7)   INIT_UCOL(u8, 8)
    INIT_UCOL(u9, 9)   INIT_UCOL(u10, 10) INIT_UCOL(u11, 11)

    // ---- one-time: LDS-resident U, padded region (cols j=12..14) ----
    // col cidx=3*gg+(j-12), pair p: byte = cidx*640 + (p>>4)*80 + (p&15)*4
    for (int idx = tau; idx < 192 * 128; idx += NT) {
        const int cidx = idx >> 7, p = idx & 127;
        const int gg = cidx / 3, jj = cidx % 3;
        const int col = 16 * gg + 12 + jj;
        U32H2 a;
        a.h = f16x2{(_Float16)Um[(size_t)(2 * p) * G4 + col],
                    (_Float16)Um[(size_t)(2 * p + 1) * G4 + col]};
        *(unsigned int*)(smem + cidx * 640 + (p >> 4) * 80 + (p & 15) * 4) = a.u;
    }
    // ---- one-time: LDS-resident U, swizzled region (col j=15) ----
    // quad i of slice s stored at physical quad (i ^ (s&3))
    for (int idx = tau; idx < 64 * 128; idx += NT) {
        const int cidx = idx >> 7, p = idx & 127;
        const int col = 16 * cidx + 15;
        const int s = p >> 4, iq = (p >> 2) & 3, e = p & 3;
        U32H2 a;
        a.h = f16x2{(_Float16)Um[(size_t)(2 * p) * G4 + col],
                    (_Float16)Um[(size_t)(2 * p + 1) * G4 + col]};
        *(unsigned int*)(smem + UUNP_OFF + cidx * 512 + s * 64 +
                         ((iq ^ (s & 3)) << 4) + e * 4) = a.u;
    }
    // ---- init h = 0 ----
    if (tau < U_) h16[(tau >> 5) * 40 + (tau & 31)] = 0;

    const float dwr = (tau < U_) ? dw[tau] : 0.f;
    const float db0 = dbp[0];
    float c_state = 0.f;

    // per-thread LDS read bases (set once)
    const uint4* lqP  = (const uint4*)(smem + (3 * g) * 640 + r * 80);
    const uint4* lqU0 = (const uint4*)(smem + UUNP_OFF + g * 512 + r * 64 + (((0 ^ (r & 3))) << 4));
    const uint4* lqU1 = (const uint4*)(smem + UUNP_OFF + g * 512 + r * 64 + (((1 ^ (r & 3))) << 4));
    const uint4* lqU2 = (const uint4*)(smem + UUNP_OFF + g * 512 + r * 64 + (((2 ^ (r & 3))) << 4));
    const uint4* lqU3 = (const uint4*)(smem + UUNP_OFF + g * 512 + r * 64 + (((3 ^ (r & 3))) << 4));
    const uint4* hq   = (const uint4*)(smem + H_OFF + r * 80);
    const int c2 = 16 * g + 2 * r;              // the two z columns this thread owns

    float2 xzc = *(const float2*)(xz + (size_t)b * G4 + c2);   // t=0
    __syncthreads();

    for (int t = 0; t < T_; ++t) {
        // prefetch next step's xz (hides L2/L3 latency under the dot phase)
        const int tn = (t + 1 < T_) ? t + 1 : t;
        const float2 xzn = *(const float2*)(xz + ((size_t)tn * B_ + b) * G4 + c2);

        // ---- partial dots over this slice's 32 k values, 16 columns ----
        float acc0 = 0.f, acc1 = 0.f, acc2 = 0.f, acc3 = 0.f;
        float acc4 = 0.f, acc5 = 0.f, acc6 = 0.f, acc7 = 0.f;
        float acc8 = 0.f, acc9 = 0.f, acc10 = 0.f, acc11 = 0.f;
        float acc12 = 0.f, acc13 = 0.f, acc14 = 0.f, acc15 = 0.f;

        DOT_CHUNK(0, s0, s1, s2, s3)
        DOT_CHUNK(1, s4, s5, s6, s7)
        DOT_CHUNK(2, s8, s9, sa, sb)
        DOT_CHUNK(3, sc, sd, se, sf)

        // ---- 8-lane butterfly reduce on the VALU/DPP pipe ----
        RED(acc0)  RED(acc1)  RED(acc2)  RED(acc3)
        RED(acc4)  RED(acc5)  RED(acc6)  RED(acc7)
        RED(acc8)  RED(acc9)  RED(acc10) RED(acc11)
        RED(acc12) RED(acc13) RED(acc14) RED(acc15)

        // lane r keeps columns 2r, 2r+1
        float z0 = acc0, z1 = acc1;
        if (r == 1) { z0 = acc2;  z1 = acc3;  }
        if (r == 2) { z0 = acc4;  z1 = acc5;  }
        if (r == 3) { z0 = acc6;  z1 = acc7;  }
        if (r == 4) { z0 = acc8;  z1 = acc9;  }
        if (r == 5) { z0 = acc10; z1 = acc11; }
        if (r == 6) { z0 = acc12; z1 = acc13; }
        if (r == 7) { z0 = acc14; z1 = acc15; }
        z0 += xzc.x;
        z1 += xzc.y;
        *(float2*)(z_s + c2) = float2{z0, z1};
        __syncthreads();                        // z ready

        // ---- gates + state update (threads tau < 256, u = tau) ----
        if (tau < U_) {
            const int u = tau;
            float zi = z_s[u];
            float zf = z_s[U_ + u];
            float zg = z_s[2 * U_ + u];
            float zo = z_s[3 * U_ + u];
            float ig = sigmoidf_(zi);
            float fg = sigmoidf_(zf);
            float gg = fmaxf(zg, 0.f);
            float og = sigmoidf_(zo);
            c_state = fg * c_state + ig * gg;
            float h = og * fmaxf(c_state, 0.f);
            U32H2 hb; hb.h = f16x2{(_Float16)h, (_Float16)h};
            h16[(u >> 5) * 40 + (u & 31)] = hb.s[0];
            pd_s[u] = h * dwr;
        }
        __syncthreads();                        // h (and pd) ready

        // ---- dense: sigma[b][t] = sum_u h[u]*dw[u] + db ----
        if (tau < 64) {
            float s = pd_s[tau] + pd_s[tau + 64] + pd_s[tau + 128] + pd_s[tau + 192];
            #pragma unroll
            for (int off = 32; off > 0; off >>= 1)
                s += __shfl_down(s, off);
            if (tau == 0) out[(size_t)b * T_ + t] = s + db0;
        }

        xzc = xzn;
    }
}

// ---------------------------------------------------------------------------
// Fallback (no workspace): streaming kernel, correctness only.
// ---------------------------------------------------------------------------
__global__ __launch_bounds__(1024) void lstm_fallback(
        const float* __restrict__ x,  const float* __restrict__ W,
        const float* __restrict__ Um, const float* __restrict__ bias,
        const float* __restrict__ dw, const float* __restrict__ dbp,
        float* __restrict__ out) {
    __shared__ float h_s[U_];
    __shared__ float z_s2[G4];
    __shared__ float pd_s2[U_];
    const int g = threadIdx.x;
    const int b = blockIdx.x;
    const float bg  = bias[g];
    const float dwr = (g < U_) ? dw[g] : 0.f;
    const float db0 = dbp[0];
    float c = 0.f;
    if (g < U_) h_s[g] = 0.f;
    __syncthreads();
    const float* Ucol = Um + g;
    for (int t = 0; t < T_; ++t) {
        float acc = bg;
        const float* xrow = x + ((size_t)b * T_ + t) * D_;
        for (int d = 0; d < D_; ++d) acc += xrow[d] * W[(size_t)d * G4 + g];
        for (int k = 0; k < U_; ++k) acc += h_s[k] * Ucol[(size_t)k * G4];
        z_s2[g] = acc;
        __syncthreads();
        if (g < U_) {
            float ig = sigmoidf_(z_s2[g]);
            float fg = sigmoidf_(z_s2[U_ + g]);
            float gg = fmaxf(z_s2[2 * U_ + g], 0.f);
            float og = sigmoidf_(z_s2[3 * U_ + g]);
            c = fg * c + ig * gg;
            float h = og * fmaxf(c, 0.f);
            h_s[g] = h; pd_s2[g] = h * dwr;
        }
        __syncthreads();
        if (g < 64) {
            float s = pd_s2[g] + pd_s2[g + 64] + pd_s2[g + 128] + pd_s2[g + 192];
            #pragma unroll
            for (int off = 32; off > 0; off >>= 1) s += __shfl_down(s, off);
            if (g == 0) out[(size_t)b * T_ + t] = s + db0;
        }
        __syncthreads();
    }
}

// ---------------------------------------------------------------------------
extern "C" void kernel_launch(void* const* d_in, const int* in_sizes, int n_in,
                              void* d_out, int out_size, void* d_ws, size_t ws_size,
                              hipStream_t stream) {
    const float* x    = (const float*)d_in[0];
    const float* W    = (const float*)d_in[1];
    const float* Um   = (const float*)d_in[2];
    const float* bias = (const float*)d_in[3];
    const float* dw   = (const float*)d_in[4];
    const float* db   = (const float*)d_in[5];
    float* out = (float*)d_out;

    const size_t need = (size_t)T_ * B_ * G4 * sizeof(float);   // 128 MiB
    if (ws_size >= need) {
        float* xz = (float*)d_ws;
        dim3 gridX(G4 / 256, (T_ * B_) / 16);
        xz_kernel<<<gridX, 256, 0, stream>>>(x, W, bias, xz);

        static bool attr_done = false;  // idempotent config, not a work guard
        if (!attr_done) {
            hipFuncSetAttribute((const void*)lstm_kernel,
                                hipFuncAttributeMaxDynamicSharedMemorySize,
                                (int)(160 * 1024));
            attr_done = true;
        }
        lstm_kernel<<<B_, NT, SMEM_TOTAL, stream>>>(Um, dw, db, xz, out);
    } else {
        lstm_fallback<<<B_, 1024, 0, stream>>>(x, W, Um, bias, dw, db, out);
    }
}